// Round 8
// baseline (252.336 us; speedup 1.0000x reference)
//
#include <hip/hip_runtime.h>
#include <cmath>

#define T_LEN 480000
#define BATCH 64
#define L     64                 // samples per thread (chunk)
#define WARMT 6                  // warm threads per block (provisional-only)
#define OUTT  (256 - WARMT)      // 250 output chunks per block
#define SPB   (OUTT * L)         // 16000 output samples per block
#define BPR   (T_LEN / SPB)      // 30 blocks per row (exact)

// ---- compile-time coefficient + homogeneous-basis tables ----------------
constexpr double kPI = 3.14159265358979323846;
constexpr double csin(double x){ double t=x,s=x; for(int i=1;i<14;++i){ t*=-x*x/double((2*i)*(2*i+1)); s+=t;} return s; }
constexpr double ccos(double x){ double t=1,s=1; for(int i=1;i<14;++i){ t*=-x*x/double((2*i-1)*(2*i)); s+=t;} return s; }

struct Tab { float U[L]; float W[L]; float b0,b1,b2,c1,c2; };
constexpr Tab make_tab(){
    Tab t{};
    const double w0    = 2.0*kPI*100.0/16000.0;
    const double alpha = csin(w0)/(2.0*0.7071067811865476);
    const double cw    = ccos(w0);
    const double a0    = 1.0+alpha;
    const double b0 = (1.0+cw)/2.0/a0, b1 = -(1.0+cw)/a0, b2 = b0;
    const double c1 = 2.0*cw/a0;        // -a1/a0
    const double c2 = -(1.0-alpha)/a0;  // -a2/a0
    t.b0=(float)b0; t.b1=(float)b1; t.b2=(float)b2; t.c1=(float)c1; t.c2=(float)c2;
    double u1=1.0,u2=0.0,w1=0.0,w2=1.0;
    for(int n=0;n<L;++n){
        const double u = c1*u1 + c2*u2, w = c1*w1 + c2*w2;
        t.U[n]=(float)u; t.W[n]=(float)w;
        u2=u1; u1=u; w2=w1; w1=w;
    }
    return t;
}
constexpr Tab TAB = make_tab();

// One biquad DF1 step; single dependent FMA on the y-critical path.
#define STEP(xi, yo) do {                                   \
    float f_  = fmaf(b0, (xi), fmaf(b1, x1, b2 * x2));      \
    float g_  = fmaf(c2, y2, f_);                           \
    float yy_ = fmaf(c1, y1, g_);                           \
    x2 = x1; x1 = (xi);                                     \
    y2 = y1; y1 = yy_;                                      \
    (yo) = yy_;                                             \
} while (0)

// amdgpu_waves_per_eu(4,4): rounds 4/6/7 all came back VGPR=44 — the pre-RA
// scheduler targets 8 waves/EU and sinks loads to consumers (~2 in flight,
// 2.5 TB/s plateau). Capping MAX waves/EU at 4 removes the incentive to stay
// under 64 VGPRs, so the hoisted 16-load burst + live p[] survive scheduling.
__global__ __launch_bounds__(256) __attribute__((amdgpu_waves_per_eu(4, 4)))
void highpass_kernel(
    const float* __restrict__ in, float* __restrict__ out,
    const float4 M1, const float4 M2, const float4 M3,
    const float4 M4, const float4 M5)
{
    constexpr float b0=TAB.b0, b1=TAB.b1, b2=TAB.b2, c1=TAB.c1, c2=TAB.c2;

    const int r = blockIdx.x / BPR;
    const int b = blockIdx.x - r * BPR;
    const int t = threadIdx.x;
    const size_t rowoff = (size_t)r * T_LEN;
    const int start = b * SPB + (t - WARMT) * L;  // <0 only for warm threads of block 0

    float4 p[16];                 // provisional outputs, MUST stay in regs
    float pa = 0.f, pb = 0.f;

    const bool active = (start >= 0);
    if (active) {
        float xs1 = 0.f, xs2 = 0.f;
        if (start > 0) {
            xs1 = in[rowoff + start - 1];
            xs2 = in[rowoff + start - 2];
        }
        const float4* __restrict__ xv = (const float4*)(in + rowoff + start);
        float4 v[16];
#pragma unroll
        for (int i = 0; i < 16; ++i) v[i] = xv[i];   // 16 loads in flight
        float x1 = xs1, x2 = xs2, y1 = 0.f, y2 = 0.f;
#pragma unroll
        for (int i = 0; i < 16; ++i) {               // v[i] dies as p[i] is born
            float4 q;
            STEP(v[i].x, q.x); STEP(v[i].y, q.y);
            STEP(v[i].z, q.z); STEP(v[i].w, q.w);
            p[i] = q;
        }
        pa = y1; pb = y2;
    }

    __shared__ float2 pl[256];
    pl[t] = make_float2(pa, pb);
    __syncthreads();
    if (t < WARMT) return;        // warm threads done

    // True incoming state: S_{t-1} = p_{t-1} + M p_{t-2} + ... + M^5 p_{t-6}
    // (M = A^64, ||M^6|| ~ 2e-5 -> truncation negligible)
    const float2 q1 = pl[t - 1], q2 = pl[t - 2], q3 = pl[t - 3],
                 q4 = pl[t - 4], q5 = pl[t - 5], q6 = pl[t - 6];
    float Y1 = q1.x, Y2 = q1.y;
    Y1 = fmaf(M1.x, q2.x, fmaf(M1.y, q2.y, Y1));
    Y2 = fmaf(M1.z, q2.x, fmaf(M1.w, q2.y, Y2));
    Y1 = fmaf(M2.x, q3.x, fmaf(M2.y, q3.y, Y1));
    Y2 = fmaf(M2.z, q3.x, fmaf(M2.w, q3.y, Y2));
    Y1 = fmaf(M3.x, q4.x, fmaf(M3.y, q4.y, Y1));
    Y2 = fmaf(M3.z, q4.x, fmaf(M3.w, q4.y, Y2));
    Y1 = fmaf(M4.x, q5.x, fmaf(M4.y, q5.y, Y1));
    Y2 = fmaf(M4.z, q5.x, fmaf(M4.w, q5.y, Y2));
    Y1 = fmaf(M5.x, q6.x, fmaf(M5.y, q6.y, Y1));
    Y2 = fmaf(M5.z, q6.x, fmaf(M5.w, q6.y, Y2));

    // Pass B: y[n] = p[n] + Y1*U[n] + Y2*W[n]  (2 independent FMAs/sample,
    // fused with the store loop — no serial recurrence, no re-load of x)
    float4* __restrict__ yv = (float4*)(out + rowoff + start);
#pragma unroll
    for (int i = 0; i < 16; ++i) {
        float4 q = p[i];
        q.x = fmaf(Y1, TAB.U[4*i+0], fmaf(Y2, TAB.W[4*i+0], q.x));
        q.y = fmaf(Y1, TAB.U[4*i+1], fmaf(Y2, TAB.W[4*i+1], q.y));
        q.z = fmaf(Y1, TAB.U[4*i+2], fmaf(Y2, TAB.W[4*i+2], q.z));
        q.w = fmaf(Y1, TAB.U[4*i+3], fmaf(Y2, TAB.W[4*i+3], q.w));
        yv[i] = q;
    }
}

static void matmul2(const double* a, const double* bm, double* o) {
    o[0] = a[0]*bm[0] + a[1]*bm[2];
    o[1] = a[0]*bm[1] + a[1]*bm[3];
    o[2] = a[2]*bm[0] + a[3]*bm[2];
    o[3] = a[2]*bm[1] + a[3]*bm[3];
}

extern "C" void kernel_launch(void* const* d_in, const int* in_sizes, int n_in,
                              void* d_out, int out_size, void* d_ws, size_t ws_size,
                              hipStream_t stream) {
    const float* in  = (const float*)d_in[0];
    float*       out = (float*)d_out;

    // Host-side double-precision coefficients for the reconstruction matrices
    const double Q     = 0.7071067811865476;
    const double w0    = 2.0 * M_PI * 100.0 / 16000.0;
    const double alpha = sin(w0) / (2.0 * Q);
    const double cosw  = cos(w0);
    const double a0d = 1.0 + alpha;
    const double c1d = 2.0 * cosw / a0d;       // -a1/a0
    const double c2d = -(1.0 - alpha) / a0d;   // -a2/a0

    // M = A^L (A = [[c1,c2],[1,0]]) via repeated squaring, then powers M^1..M^5
    double A[4] = {c1d, c2d, 1.0, 0.0};
    double M[4] = {A[0], A[1], A[2], A[3]};
    for (int s = 0; s < 6; ++s) {              // A^2 ... A^64  (L=64)
        double tmp[4]; matmul2(M, M, tmp);
        M[0]=tmp[0]; M[1]=tmp[1]; M[2]=tmp[2]; M[3]=tmp[3];
    }
    double P[5][4];
    P[0][0]=M[0]; P[0][1]=M[1]; P[0][2]=M[2]; P[0][3]=M[3];
    for (int k = 1; k < 5; ++k) matmul2(P[k-1], M, P[k]);

    float4 Mv[5];
    for (int k = 0; k < 5; ++k)
        Mv[k] = make_float4((float)P[k][0], (float)P[k][1],
                            (float)P[k][2], (float)P[k][3]);

    const int grid = BATCH * BPR;   // 1920 blocks x 256 threads = 7680 waves
    hipLaunchKernelGGL(highpass_kernel, dim3(grid), dim3(256), 0, stream,
                       in, out, Mv[0], Mv[1], Mv[2], Mv[3], Mv[4]);
}

// Round 9
// 238.618 us; speedup vs baseline: 1.0575x; 1.0575x over previous
//
#include <hip/hip_runtime.h>
#include <cmath>

#define T_LEN 480000
#define BATCH 64
#define L     64                 // samples per thread (chunk)
#define WARMT 6                  // warm threads per block (provisional-only)
#define OUTT  (256 - WARMT)      // 250 output chunks per block
#define SPB   (OUTT * L)         // 16000 output samples per block
#define BPR   (T_LEN / SPB)      // 30 blocks per row (exact)

// ---- compile-time coefficient + homogeneous-basis tables ----------------
constexpr double kPI = 3.14159265358979323846;
constexpr double csin(double x){ double t=x,s=x; for(int i=1;i<14;++i){ t*=-x*x/double((2*i)*(2*i+1)); s+=t;} return s; }
constexpr double ccos(double x){ double t=1,s=1; for(int i=1;i<14;++i){ t*=-x*x/double((2*i-1)*(2*i)); s+=t;} return s; }

struct Tab { float U[L]; float W[L]; float b0,b1,b2,c1,c2; };
constexpr Tab make_tab(){
    Tab t{};
    const double w0    = 2.0*kPI*100.0/16000.0;
    const double alpha = csin(w0)/(2.0*0.7071067811865476);
    const double cw    = ccos(w0);
    const double a0    = 1.0+alpha;
    const double b0 = (1.0+cw)/2.0/a0, b1 = -(1.0+cw)/a0, b2 = b0;
    const double c1 = 2.0*cw/a0;        // -a1/a0
    const double c2 = -(1.0-alpha)/a0;  // -a2/a0
    t.b0=(float)b0; t.b1=(float)b1; t.b2=(float)b2; t.c1=(float)c1; t.c2=(float)c2;
    double u1=1.0,u2=0.0,w1=0.0,w2=1.0;
    for(int n=0;n<L;++n){
        const double u = c1*u1 + c2*u2, w = c1*w1 + c2*w2;
        t.U[n]=(float)u; t.W[n]=(float)w;
        u2=u1; u1=u; w2=w1; w1=w;
    }
    return t;
}
constexpr Tab TAB = make_tab();

// One biquad DF1 step; single dependent FMA on the y-critical path.
#define STEP(xi, yo) do {                                   \
    float f_  = fmaf(b0, (xi), fmaf(b1, x1, b2 * x2));      \
    float g_  = fmaf(c2, y2, f_);                           \
    float yy_ = fmaf(c1, y1, g_);                           \
    x2 = x1; x1 = (xi);                                     \
    y2 = y1; y1 = yy_;                                      \
    (yo) = yy_;                                             \
} while (0)

// Rounds 6/7/8: occupancy hints never stopped the allocator from sinking /
// re-loading v[i] at its use (VGPR stayed 44-52, ~0.3 loads in flight/wave,
// 2.5 TB/s plateau). The asm memory barrier below makes sinking AND
// reload-rematerialization ILLEGAL: loads must issue before it, values must
// live in registers (or scratch) after it. Backend then emits counted
// vmcnt(N) waits -> scan overlaps the remaining in-flight loads.
__global__ __launch_bounds__(256, 4) void highpass_kernel(
    const float* __restrict__ in, float* __restrict__ out,
    const float4 M1, const float4 M2, const float4 M3,
    const float4 M4, const float4 M5)
{
    constexpr float b0=TAB.b0, b1=TAB.b1, b2=TAB.b2, c1=TAB.c1, c2=TAB.c2;

    const int r = blockIdx.x / BPR;
    const int b = blockIdx.x - r * BPR;
    const int t = threadIdx.x;
    const size_t rowoff = (size_t)r * T_LEN;
    const int start = b * SPB + (t - WARMT) * L;  // <0 only for warm threads of block 0

    float4 p[16];                 // provisional outputs (serial-scan result)
    float pa = 0.f, pb = 0.f;

    const bool active = (start >= 0);
    if (active) {
        const float4* __restrict__ xv = (const float4*)(in + rowoff + start);
        float4 v[16];
#pragma unroll
        for (int i = 0; i < 16; ++i) v[i] = xv[i];   // 16-load burst, 16 KB/wave
        float xs1 = 0.f, xs2 = 0.f;
        if (start > 0) {
            xs1 = in[rowoff + start - 1];
            xs2 = in[rowoff + start - 2];
        }
        // Pin: loads may not sink below, values may not be re-loaded above.
        asm volatile("" ::: "memory");

        float x1 = xs1, x2 = xs2, y1 = 0.f, y2 = 0.f;
#pragma unroll
        for (int i = 0; i < 16; ++i) {               // v[i] dies as p[i] is born
            float4 q;
            STEP(v[i].x, q.x); STEP(v[i].y, q.y);
            STEP(v[i].z, q.z); STEP(v[i].w, q.w);
            p[i] = q;
        }
        pa = y1; pb = y2;
    }

    __shared__ float2 pl[256];
    pl[t] = make_float2(pa, pb);
    __syncthreads();
    if (t < WARMT) return;        // warm threads done

    // True incoming state: S_{t-1} = p_{t-1} + M p_{t-2} + ... + M^5 p_{t-6}
    // (M = A^64, ||M^6|| ~ 2e-5 -> truncation negligible)
    const float2 q1 = pl[t - 1], q2 = pl[t - 2], q3 = pl[t - 3],
                 q4 = pl[t - 4], q5 = pl[t - 5], q6 = pl[t - 6];
    float Y1 = q1.x, Y2 = q1.y;
    Y1 = fmaf(M1.x, q2.x, fmaf(M1.y, q2.y, Y1));
    Y2 = fmaf(M1.z, q2.x, fmaf(M1.w, q2.y, Y2));
    Y1 = fmaf(M2.x, q3.x, fmaf(M2.y, q3.y, Y1));
    Y2 = fmaf(M2.z, q3.x, fmaf(M2.w, q3.y, Y2));
    Y1 = fmaf(M3.x, q4.x, fmaf(M3.y, q4.y, Y1));
    Y2 = fmaf(M3.z, q4.x, fmaf(M3.w, q4.y, Y2));
    Y1 = fmaf(M4.x, q5.x, fmaf(M4.y, q5.y, Y1));
    Y2 = fmaf(M4.z, q5.x, fmaf(M4.w, q5.y, Y2));
    Y1 = fmaf(M5.x, q6.x, fmaf(M5.y, q6.y, Y1));
    Y2 = fmaf(M5.z, q6.x, fmaf(M5.w, q6.y, Y2));

    // Pass B: y[n] = p[n] + Y1*U[n] + Y2*W[n]  (2 independent FMAs/sample,
    // fused with the store loop — no serial recurrence, no re-read of x)
    float4* __restrict__ yv = (float4*)(out + rowoff + start);
#pragma unroll
    for (int i = 0; i < 16; ++i) {
        float4 q = p[i];
        q.x = fmaf(Y1, TAB.U[4*i+0], fmaf(Y2, TAB.W[4*i+0], q.x));
        q.y = fmaf(Y1, TAB.U[4*i+1], fmaf(Y2, TAB.W[4*i+1], q.y));
        q.z = fmaf(Y1, TAB.U[4*i+2], fmaf(Y2, TAB.W[4*i+2], q.z));
        q.w = fmaf(Y1, TAB.U[4*i+3], fmaf(Y2, TAB.W[4*i+3], q.w));
        yv[i] = q;
    }
}

static void matmul2(const double* a, const double* bm, double* o) {
    o[0] = a[0]*bm[0] + a[1]*bm[2];
    o[1] = a[0]*bm[1] + a[1]*bm[3];
    o[2] = a[2]*bm[0] + a[3]*bm[2];
    o[3] = a[2]*bm[1] + a[3]*bm[3];
}

extern "C" void kernel_launch(void* const* d_in, const int* in_sizes, int n_in,
                              void* d_out, int out_size, void* d_ws, size_t ws_size,
                              hipStream_t stream) {
    const float* in  = (const float*)d_in[0];
    float*       out = (float*)d_out;

    // Host-side double-precision coefficients for the reconstruction matrices
    const double Q     = 0.7071067811865476;
    const double w0    = 2.0 * M_PI * 100.0 / 16000.0;
    const double alpha = sin(w0) / (2.0 * Q);
    const double cosw  = cos(w0);
    const double a0d = 1.0 + alpha;
    const double c1d = 2.0 * cosw / a0d;       // -a1/a0
    const double c2d = -(1.0 - alpha) / a0d;   // -a2/a0

    // M = A^L (A = [[c1,c2],[1,0]]) via repeated squaring, then powers M^1..M^5
    double A[4] = {c1d, c2d, 1.0, 0.0};
    double M[4] = {A[0], A[1], A[2], A[3]};
    for (int s = 0; s < 6; ++s) {              // A^2 ... A^64  (L=64)
        double tmp[4]; matmul2(M, M, tmp);
        M[0]=tmp[0]; M[1]=tmp[1]; M[2]=tmp[2]; M[3]=tmp[3];
    }
    double P[5][4];
    P[0][0]=M[0]; P[0][1]=M[1]; P[0][2]=M[2]; P[0][3]=M[3];
    for (int k = 1; k < 5; ++k) matmul2(P[k-1], M, P[k]);

    float4 Mv[5];
    for (int k = 0; k < 5; ++k)
        Mv[k] = make_float4((float)P[k][0], (float)P[k][1],
                            (float)P[k][2], (float)P[k][3]);

    const int grid = BATCH * BPR;   // 1920 blocks x 256 threads = 7680 waves
    hipLaunchKernelGGL(highpass_kernel, dim3(grid), dim3(256), 0, stream,
                       in, out, Mv[0], Mv[1], Mv[2], Mv[3], Mv[4]);
}